// Round 4
// baseline (1594.137 us; speedup 1.0000x reference)
//
#include <hip/hip_runtime.h>

#define NQ 64
#define ND 50000
#define QTOK 32
#define DTOK 16
#define EMB 768
#define HID 512

typedef short s16x8 __attribute__((ext_vector_type(8)));
typedef float f32x4 __attribute__((ext_vector_type(4)));

// ---------- bf16 helpers (RNE) ----------
__device__ __forceinline__ unsigned short f2bf(float f) {
    union { float f; unsigned u; } x; x.f = f;
    unsigned r = x.u + 0x7fffu + ((x.u >> 16) & 1u);
    return (unsigned short)(r >> 16);
}
__device__ __forceinline__ float bf2f(unsigned short h) {
    union { unsigned u; float f; } x; x.u = ((unsigned)h) << 16;
    return x.f;
}
// activation stream triple (hi,lo,hi) per element pair -> handled per element below
__device__ __forceinline__ void packA1(float v, ushort* p) {  // A-side triple for one element
    unsigned short hi = f2bf(v);
    unsigned short lo = f2bf(v - bf2f(hi));
    p[0] = hi; p[1] = lo; p[2] = hi;
}
__device__ __forceinline__ void packB1(float v, ushort* p) {  // B-side triple
    unsigned short hi = f2bf(v);
    unsigned short lo = f2bf(v - bf2f(hi));
    p[0] = hi; p[1] = hi; p[2] = lo;
}
// pair-pack for pool (A-side): (va,vb) -> 3 uints
__device__ __forceinline__ void pack2A(float va, float vb, unsigned& w0, unsigned& w1, unsigned& w2) {
    unsigned ha = f2bf(va); unsigned la = f2bf(va - bf2f((unsigned short)ha));
    unsigned hb = f2bf(vb); unsigned lb = f2bf(vb - bf2f((unsigned short)hb));
    w0 = ha | (la << 16);
    w1 = ha | (hb << 16);
    w2 = lb | (hb << 16);
}

__device__ __forceinline__ void gload_lds16(const void* g, void* l) {
    __builtin_amdgcn_global_load_lds(
        (const __attribute__((address_space(1))) void*)g,
        (__attribute__((address_space(3))) void*)l, 16, 0, 0);
}

// ---------------- mean-pool -> augmented A-side bf16 [rows][3*EMB] ----------------
__global__ void pool_aug(const float* __restrict__ in, ushort* __restrict__ out, int T) {
    int r = blockIdx.x, t = threadIdx.x;  // 192 threads x 4 floats
    const float4* ip = (const float4*)in + (size_t)r * T * (EMB / 4) + t;
    float4 a = make_float4(0.f, 0.f, 0.f, 0.f);
    for (int i = 0; i < T; ++i) {
        float4 v = ip[(size_t)i * (EMB / 4)];
        a.x += v.x; a.y += v.y; a.z += v.z; a.w += v.w;
    }
    const float s = 1.0f / (float)T;
    unsigned w0, w1, w2, w3, w4, w5;
    pack2A(a.x * s, a.y * s, w0, w1, w2);
    pack2A(a.z * s, a.w * s, w3, w4, w5);
    uint2* q = (uint2*)(out + (size_t)r * (3 * EMB) + t * 12);
    q[0] = make_uint2(w0, w1); q[1] = make_uint2(w2, w3); q[2] = make_uint2(w4, w5);
}

// ---------------- weight convert: W[K][512] fp32 -> Wp[512][3K] bf16 (hi,hi,lo) ----------------
__global__ void wconv(const float* __restrict__ W, ushort* __restrict__ Wp, int K) {
    int n = blockIdx.x;  // 512 blocks
    for (int k = threadIdx.x; k < K; k += blockDim.x) {
        float v = W[(size_t)k * HID + n];
        ushort* p = Wp + (size_t)n * 3 * K + 3 * k;
        packB1(v, p);
    }
}

// ---------------- unified fused MFMA GEMM ----------------
// Tile 64 x (NW*64); NW waves, wave wc owns 64x64 at col panel wc. BK=64.
// A' [M][K2] (hi,lo,hi); B' [rowsB][K2] (hi,hi,lo). XOR-swizzled LDS (16B slots).
// EPI 0: relu(acc+bias) -> augA out[M][3*512]
// EPI 1: LayerNorm(acc+bias; gamma,beta) -> augA out[M][3*512]
// EPI 2: L2norm(acc+bias) -> augA out[M][3*512]   (query final)
// EPI 3: L2norm(acc+bias) -> augB out[M][3*512]   (doc final)
// EPI 4: scores: fp32 out[M][ldo] = acc * (1/temp[0]), col guard N_B
template <int EPI, int NW>
__global__ __launch_bounds__(NW * 64) void gemmF(const ushort* __restrict__ A,
                                                 const ushort* __restrict__ B,
                                                 const float* __restrict__ bias,
                                                 const float* __restrict__ gamma,
                                                 const float* __restrict__ beta,
                                                 void* __restrict__ out,
                                                 int M, int N_B, int K2, long ldo,
                                                 const float* __restrict__ temp) {
    constexpr int BN = NW * 64;
    constexpr int NTHR = NW * 64;
    __shared__ ushort As[64 * 64];      // 8 KB
    __shared__ ushort Bs[BN * 64];      // NW*8 KB
    __shared__ float red[2][NW][64];
    __shared__ float mu_s[64], rs_s[64];
    const int bm = blockIdx.x * 64;
    const int bn = blockIdx.y * BN;
    const int tid = threadIdx.x;
    const int lane = tid & 63;
    const int wc = tid >> 6;            // wave = col panel
    f32x4 acc[4][4] = {};

    for (int k0 = 0; k0 < K2; k0 += 64) {
        // stage A: 512 x 16B chunks, linear LDS dest (lane*16B), swizzled global k-slot
        #pragma unroll
        for (int c = 0; c < 512 / NTHR; ++c) {
            int idx = c * NTHR + tid;
            int row = idx >> 3, s = idx & 7;
            int gr = bm + row; if (gr >= M) gr = M - 1;
            int ks = (s ^ (row & 7)) << 3;
            gload_lds16(A + (size_t)gr * K2 + k0 + ks, As + idx * 8);
        }
        // stage B: NW*512 chunks -> 8 rounds
        #pragma unroll
        for (int c = 0; c < 8; ++c) {
            int idx = c * NTHR + tid;
            int n = idx >> 3, s = idx & 7;
            int gn = bn + n; if (gn >= N_B) gn = N_B - 1;
            int ks = (s ^ (n & 7)) << 3;
            gload_lds16(B + (size_t)gn * K2 + k0 + ks, Bs + idx * 8);
        }
        __syncthreads();

        #pragma unroll
        for (int kk = 0; kk < 2; ++kk) {
            const int sp = kk * 4 + (lane >> 4);
            s16x8 a[4], b[4];
            #pragma unroll
            for (int i = 0; i < 4; ++i) {
                int r = i * 16 + (lane & 15);
                a[i] = *(const s16x8*)(As + r * 64 + ((sp ^ (r & 7)) << 3));
            }
            #pragma unroll
            for (int j = 0; j < 4; ++j) {
                int n = wc * 64 + j * 16 + (lane & 15);
                b[j] = *(const s16x8*)(Bs + n * 64 + ((sp ^ (n & 7)) << 3));
            }
            #pragma unroll
            for (int i = 0; i < 4; ++i)
                #pragma unroll
                for (int j = 0; j < 4; ++j)
                    acc[i][j] = __builtin_amdgcn_mfma_f32_16x16x32_bf16(a[i], b[j], acc[i][j], 0, 0, 0);
        }
        __syncthreads();
    }

    // ---- epilogue; C/D layout: row = i*16 + (lane>>4)*4 + r, col = wc*64 + j*16 + (lane&15)
    if (EPI == 4) {
        float invT = 1.0f / temp[0];
        #pragma unroll
        for (int j = 0; j < 4; ++j) {
            int gcol = bn + wc * 64 + j * 16 + (lane & 15);
            #pragma unroll
            for (int i = 0; i < 4; ++i)
                #pragma unroll
                for (int r = 0; r < 4; ++r) {
                    int grow = bm + i * 16 + ((lane >> 4) << 2) + r;
                    if (grow < M && gcol < N_B)
                        ((float*)out)[(size_t)grow * ldo + gcol] = acc[i][j][r] * invT;
                }
        }
        return;
    }

    // bias per col (bn==0 for these epilogues; BN==512)
    float bv[4];
    #pragma unroll
    for (int j = 0; j < 4; ++j) bv[j] = bias[wc * 64 + j * 16 + (lane & 15)];

    if (EPI == 1 || EPI == 2 || EPI == 3) {
        // row reductions: sum (LN only) and sum-of-squares
        #pragma unroll
        for (int i = 0; i < 4; ++i)
            #pragma unroll
            for (int r = 0; r < 4; ++r) {
                float ps = 0.f, pq = 0.f;
                #pragma unroll
                for (int j = 0; j < 4; ++j) {
                    float v = acc[i][j][r] + bv[j];
                    ps += v; pq += v * v;
                }
                #pragma unroll
                for (int o = 1; o < 16; o <<= 1) {
                    ps += __shfl_xor(ps, o);
                    pq += __shfl_xor(pq, o);
                }
                if ((lane & 15) == 0) {
                    int rl = i * 16 + ((lane >> 4) << 2) + r;
                    red[0][wc][rl] = ps;
                    red[1][wc][rl] = pq;
                }
            }
        __syncthreads();
        if (tid < 64) {
            float s = 0.f, q = 0.f;
            #pragma unroll
            for (int w = 0; w < NW; ++w) { s += red[0][w][tid]; q += red[1][w][tid]; }
            if (EPI == 1) {
                float mu = s * (1.0f / 512.0f);
                float var = q * (1.0f / 512.0f) - mu * mu;
                mu_s[tid] = mu;
                rs_s[tid] = rsqrtf(var + 1e-5f);
            } else {
                mu_s[tid] = 0.0f;
                rs_s[tid] = 1.0f / fmaxf(sqrtf(q), 1e-12f);
            }
        }
        __syncthreads();
    }

    float gl[4], bt[4];
    if (EPI == 1) {
        #pragma unroll
        for (int j = 0; j < 4; ++j) {
            int c = wc * 64 + j * 16 + (lane & 15);
            gl[j] = gamma[c]; bt[j] = beta[c];
        }
    }

    #pragma unroll
    for (int i = 0; i < 4; ++i)
        #pragma unroll
        for (int r = 0; r < 4; ++r) {
            int rl = i * 16 + ((lane >> 4) << 2) + r;
            int grow = bm + rl;
            if (grow >= M) continue;
            #pragma unroll
            for (int j = 0; j < 4; ++j) {
                int col = wc * 64 + j * 16 + (lane & 15);
                float v = acc[i][j][r] + bv[j];
                if (EPI == 0) v = fmaxf(v, 0.0f);
                else if (EPI == 1) v = (v - mu_s[rl]) * rs_s[rl] * gl[j] + bt[j];
                else v = v * rs_s[rl];
                ushort* op = (ushort*)out + (size_t)grow * (3 * HID) + 3 * col;
                if (EPI == 3) packB1(v, op); else packA1(v, op);
            }
        }
}

// ---------------- top-8 per row with lowest-index tie-break ----------------
__global__ __launch_bounds__(256) void topk_kernel(const float* __restrict__ scores,
                                                   float* __restrict__ out_scores,
                                                   int* __restrict__ out_idx, int N) {
    __shared__ float ls[2048];
    __shared__ int   li[2048];
    const int q   = blockIdx.x;
    const int tid = threadIdx.x;
    const float* row = scores + (size_t)q * N;
    float s[8]; int ix[8];
    #pragma unroll
    for (int i = 0; i < 8; ++i) { s[i] = -1e30f; ix[i] = 0x7fffffff; }
    for (int j = tid; j < N; j += 256) {
        float v = row[j];
        if (v > s[7]) {
            s[7] = v; ix[7] = j;
            #pragma unroll
            for (int t = 7; t > 0; --t) {
                bool sw = (s[t] > s[t-1]) || (s[t] == s[t-1] && ix[t] < ix[t-1]);
                if (sw) {
                    float tv = s[t]; s[t] = s[t-1]; s[t-1] = tv;
                    int   ti = ix[t]; ix[t] = ix[t-1]; ix[t-1] = ti;
                }
            }
        }
    }
    #pragma unroll
    for (int i = 0; i < 8; ++i) { ls[tid * 8 + i] = s[i]; li[tid * 8 + i] = ix[i]; }
    __syncthreads();
    for (int w = 64; w >= 1; w >>= 2) {
        if (tid < w) {
            #pragma unroll
            for (int i = 0; i < 8; ++i) { s[i] = -1e30f; ix[i] = 0x7fffffff; }
            #pragma unroll
            for (int c = 0; c < 32; ++c) {
                float v  = ls[tid * 32 + c];
                int   vi = li[tid * 32 + c];
                bool better = (v > s[7]) || (v == s[7] && vi < ix[7]);
                if (better) {
                    s[7] = v; ix[7] = vi;
                    #pragma unroll
                    for (int t = 7; t > 0; --t) {
                        bool sw = (s[t] > s[t-1]) || (s[t] == s[t-1] && ix[t] < ix[t-1]);
                        if (sw) {
                            float tv = s[t]; s[t] = s[t-1]; s[t-1] = tv;
                            int   ti = ix[t]; ix[t] = ix[t-1]; ix[t-1] = ti;
                        }
                    }
                }
            }
        }
        __syncthreads();
        if (tid < w) {
            #pragma unroll
            for (int i = 0; i < 8; ++i) { ls[tid * 8 + i] = s[i]; li[tid * 8 + i] = ix[i]; }
        }
        __syncthreads();
    }
    if (tid < 8) {
        out_scores[(size_t)q * 8 + tid] = ls[tid];
        out_idx[q * 8 + tid]            = li[tid];
    }
}

// ---------------- gather retrieved docs ----------------
__global__ __launch_bounds__(256) void gather_kernel(const float* __restrict__ docs,
                                                     const int* __restrict__ idx,
                                                     float* __restrict__ out) {
    const int b = blockIdx.x;
    const int d = idx[b];
    const float4* src = (const float4*)(docs + (size_t)d * DTOK * EMB);
    float4*       dst = (float4*)(out + (size_t)b * DTOK * EMB);
    for (int i = threadIdx.x; i < DTOK * EMB / 4; i += 256) dst[i] = src[i];
}

extern "C" void kernel_launch(void* const* d_in, const int* in_sizes, int n_in,
                              void* d_out, int out_size, void* d_ws, size_t ws_size,
                              hipStream_t stream) {
    const float* qe   = (const float*)d_in[0];
    const float* de   = (const float*)d_in[1];
    const float* qW1  = (const float*)d_in[2];
    const float* qb1  = (const float*)d_in[3];
    const float* qW2  = (const float*)d_in[4];
    const float* qb2  = (const float*)d_in[5];
    const float* qg   = (const float*)d_in[6];
    const float* qbe  = (const float*)d_in[7];
    const float* dW1  = (const float*)d_in[8];
    const float* db1  = (const float*)d_in[9];
    const float* dW2  = (const float*)d_in[10];
    const float* db2  = (const float*)d_in[11];
    const float* dg   = (const float*)d_in[12];
    const float* dbe  = (const float*)d_in[13];
    const float* pW   = (const float*)d_in[14];
    const float* pb   = (const float*)d_in[15];
    const float* temp = (const float*)d_in[16];

    float* out = (float*)d_out;

    // ---- workspace carve (~400 MB) ----
    char* w = (char*)d_ws;
    float*  scores = (float*)w;                 w += (size_t)NQ * ND * 4;           // 12.8 MB
    ushort* W1p    = (ushort*)w;                w += (size_t)HID * 3 * EMB * 2;     // dW1'
    ushort* W2p    = (ushort*)w;                w += (size_t)HID * 3 * HID * 2;     // dW2'
    ushort* pWp    = (ushort*)w;                w += (size_t)HID * 3 * HID * 2;     // pW'
    ushort* QW1p   = (ushort*)w;                w += (size_t)HID * 3 * EMB * 2;     // qW1'
    ushort* QW2p   = (ushort*)w;                w += (size_t)HID * 3 * HID * 2;     // qW2'
    ushort* qpool  = (ushort*)w;                w += (size_t)NQ * 3 * EMB * 2;
    ushort* qh1a   = (ushort*)w;                w += (size_t)NQ * 3 * HID * 2;
    ushort* qlna   = (ushort*)w;                w += (size_t)NQ * 3 * HID * 2;
    ushort* qaug   = (ushort*)w;                w += (size_t)NQ * 3 * HID * 2;
    int*    tidx   = (int*)w;                   w += 4096;
    ushort* pooled = (ushort*)w;                w += (size_t)ND * 3 * EMB * 2;      // 230.4 MB
    ushort* h1a    = (ushort*)w;                w += (size_t)ND * 3 * HID * 2;      // 153.6 MB
    ushort* lna    = pooled;   // LN-aug output overwrites pooled (dead after GEMM1)
    ushort* Daug   = h1a;      // wait: GEMM3 reads lna, writes Daug; h1a dead after GEMM2
    // note: GEMM2 reads h1a writes lna(=pooled space); GEMM3 reads lna writes Daug(=h1a space). safe.

    const int GMD = (ND + 63) / 64;   // 782

    // ---- weight conversion (5 mats) ----
    wconv<<<HID, 256, 0, stream>>>(dW1, W1p, EMB);
    wconv<<<HID, 256, 0, stream>>>(dW2, W2p, HID);
    wconv<<<HID, 256, 0, stream>>>(pW,  pWp, HID);
    wconv<<<HID, 256, 0, stream>>>(qW1, QW1p, EMB);
    wconv<<<HID, 256, 0, stream>>>(qW2, QW2p, HID);

    // ---- query path (MFMA, grid(1,1) per GEMM) ----
    pool_aug<<<NQ, 192, 0, stream>>>(qe, qpool, QTOK);
    gemmF<0, 8><<<dim3(1, 1), 512, 0, stream>>>(qpool, QW1p, qb1, nullptr, nullptr, qh1a,
                                                NQ, HID, 3 * EMB, 0, nullptr);
    gemmF<1, 8><<<dim3(1, 1), 512, 0, stream>>>(qh1a, QW2p, qb2, qg, qbe, qlna,
                                                NQ, HID, 3 * HID, 0, nullptr);
    gemmF<2, 8><<<dim3(1, 1), 512, 0, stream>>>(qlna, pWp, pb, nullptr, nullptr, qaug,
                                                NQ, HID, 3 * HID, 0, nullptr);

    // ---- doc path ----
    pool_aug<<<ND, 192, 0, stream>>>(de, pooled, DTOK);
    gemmF<0, 8><<<dim3(GMD, 1), 512, 0, stream>>>(pooled, W1p, db1, nullptr, nullptr, h1a,
                                                  ND, HID, 3 * EMB, 0, nullptr);
    gemmF<1, 8><<<dim3(GMD, 1), 512, 0, stream>>>(h1a, W2p, db2, dg, dbe, lna,
                                                  ND, HID, 3 * HID, 0, nullptr);
    gemmF<3, 8><<<dim3(GMD, 1), 512, 0, stream>>>(lna, pWp, pb, nullptr, nullptr, Daug,
                                                  ND, HID, 3 * HID, 0, nullptr);

    // ---- scores: [64, ND] = qaug x Daug^T * (1/T); tile 64x256, col-blocked ----
    gemmF<4, 4><<<dim3(1, (ND + 255) / 256), 256, 0, stream>>>(qaug, Daug, nullptr, nullptr, nullptr,
                                                               scores, NQ, ND, 3 * HID, (long)ND, temp);

    // ---- top-k + gather ----
    topk_kernel<<<NQ, 256, 0, stream>>>(scores, out, tidx, ND);
    gather_kernel<<<NQ * 8, 256, 0, stream>>>(de, tidx, out + NQ * 8);
}